// Round 7
// baseline (770.540 us; speedup 1.0000x reference)
//
#include <hip/hip_runtime.h>
#include <hip/hip_bf16.h>
#include <math.h>

// Problem constants
#define B_  64
#define T_  2048
#define DEC_ 1024
#define ENC_ 512
#define ATT_ 128
#define LOC_ 32
#define KW_  31

typedef __attribute__((ext_vector_type(8))) short short8;
typedef __attribute__((ext_vector_type(4))) float f32x4;
typedef __attribute__((ext_vector_type(4))) unsigned int u32x4;

__device__ inline unsigned short bf16_rn(float x) {
    unsigned int u = __builtin_bit_cast(unsigned int, x);
    unsigned int r = u + 0x7fffu + ((u >> 16) & 1u);
    return (unsigned short)(r >> 16);
}
__device__ inline float bf16_to_f(unsigned short h) {
    unsigned int u = ((unsigned int)h) << 16;
    return __builtin_bit_cast(float, u);
}

// Split 8 floats into hi/lo bf16 (bit-exact add-based RNE, packed pairs).
__device__ inline void cvt_split8_exact(const float* f, short8& hi8, short8& lo8) {
    u32x4 hw, lw;
    #pragma unroll
    for (int p = 0; p < 4; ++p) {
        float a = f[2 * p], b2 = f[2 * p + 1];
        unsigned u0 = __builtin_bit_cast(unsigned, a);
        unsigned u1 = __builtin_bit_cast(unsigned, b2);
        unsigned r0 = u0 + 0x7fffu + ((u0 >> 16) & 1u);
        unsigned r1 = u1 + 0x7fffu + ((u1 >> 16) & 1u);
        hw[p] = (r0 >> 16) | (r1 & 0xffff0000u);
        float d0 = a  - __builtin_bit_cast(float, r0 & 0xffff0000u);
        float d1 = b2 - __builtin_bit_cast(float, r1 & 0xffff0000u);
        unsigned v0 = __builtin_bit_cast(unsigned, d0);
        unsigned v1 = __builtin_bit_cast(unsigned, d1);
        unsigned s0 = v0 + 0x7fffu + ((v0 >> 16) & 1u);
        unsigned s1 = v1 + 0x7fffu + ((v1 >> 16) & 1u);
        lw[p] = (s0 >> 16) | (s1 & 0xffff0000u);
    }
    hi8 = __builtin_bit_cast(short8, hw);
    lo8 = __builtin_bit_cast(short8, lw);
}

// ---------------------------------------------------------------------------
// K1: prep (R1-verified version: Bph/Bpl frag layout Bp[(k>>5)*4096+n*32+(k&31)])
// ---------------------------------------------------------------------------
__global__ __launch_bounds__(256) void prep_kernel(
    const float* __restrict__ query, const float* __restrict__ Q_w,
    const float* __restrict__ Q_b, const float* __restrict__ conv_w,
    const float* __restrict__ loc_proj_w, const float* __restrict__ V_w,
    float* __restrict__ qbuf,
    unsigned short* __restrict__ Bph, unsigned short* __restrict__ Bpl,
    unsigned short* __restrict__ effh, unsigned short* __restrict__ effl)
{
    int bi = blockIdx.x, tid = threadIdx.x;
    if (bi < 256) {
        int b = bi >> 2, grp = bi & 3;
        __shared__ float sq[DEC_];
        *(float4*)(&sq[tid * 4]) = *(const float4*)(query + (size_t)b * DEC_ + tid * 4);
        __syncthreads();
        int w = tid >> 6, lane = tid & 63;
        int a0 = grp * 32 + w * 8;
        for (int p = 0; p < 4; ++p) {
            int a = a0 + 2 * p;
            const float* r0 = Q_w + (size_t)a * DEC_;
            const float* r1 = r0 + DEC_;
            float s0 = 0.f, s1 = 0.f;
            #pragma unroll
            for (int i = 0; i < 4; ++i) {
                float4 q0 = *(const float4*)(r0 + i * 256 + lane * 4);
                float4 q1 = *(const float4*)(r1 + i * 256 + lane * 4);
                float4 xq = *(const float4*)(sq + i * 256 + lane * 4);
                s0 += q0.x * xq.x + q0.y * xq.y + q0.z * xq.z + q0.w * xq.w;
                s1 += q1.x * xq.x + q1.y * xq.y + q1.z * xq.z + q1.w * xq.w;
            }
            #pragma unroll
            for (int m = 32; m >= 1; m >>= 1) {
                s0 += __shfl_xor(s0, m, 64);
                s1 += __shfl_xor(s1, m, 64);
            }
            if (lane == 0) {
                qbuf[b * ATT_ + a]     = s0 + Q_b[a];
                qbuf[b * ATT_ + a + 1] = s1 + Q_b[a + 1];
            }
        }
    } else if (bi == 256) {
        __shared__ float slp[ATT_ * LOC_];
        __shared__ float scw[LOC_ * KW_];
        for (int i = tid; i < ATT_ * LOC_; i += 256) slp[i] = loc_proj_w[i];
        for (int i = tid; i < LOC_ * KW_; i += 256) scw[i] = conv_w[i];
        __syncthreads();
        if (tid < ATT_) {
            int n = tid;
            for (int k = 0; k < 32; ++k) {
                float s = 0.f;
                if (k < KW_)
                    #pragma unroll
                    for (int c = 0; c < LOC_; ++c)
                        s += slp[n * LOC_ + c] * scw[c * KW_ + k];
                unsigned short h = bf16_rn(s);
                effh[n * 32 + k] = h;
                effl[n * 32 + k] = bf16_rn(s - bf16_to_f(h));
            }
        }
    } else {
        int g0 = (bi - 257) * 512;
        #pragma unroll
        for (int p = 0; p < 2; ++p) {
            int gi = g0 + p * 256 + tid;
            int n  = gi >> 7;
            int kq = (gi & 127) * 4;
            float4 v = ((const float4*)V_w)[gi];
            ushort4 h4, l4;
            h4.x = bf16_rn(v.x); l4.x = bf16_rn(v.x - bf16_to_f(h4.x));
            h4.y = bf16_rn(v.y); l4.y = bf16_rn(v.y - bf16_to_f(h4.y));
            h4.z = bf16_rn(v.z); l4.z = bf16_rn(v.z - bf16_to_f(h4.z));
            h4.w = bf16_rn(v.w); l4.w = bf16_rn(v.w - bf16_to_f(h4.w));
            int dst = (kq >> 5) * 4096 + n * 32 + (kq & 31);
            *(ushort4*)(Bph + dst) = h4;
            *(ushort4*)(Bpl + dst) = l4;
        }
    }
}

// ---------------------------------------------------------------------------
// K2 (FUSED, TLP-restructured): 2048 blocks x 128 threads; each block = TWO
// FULLY INDEPENDENT waves. Each wave: M=32 rows (its own t-chunk), N=128,
// K=512, R1-style direct-fragment split-bf16 MFMA, own local softmax stats,
// own partial context. ZERO __syncthreads in this kernel — pure wave-level
// latency overlap (m114). 16 waves/CU peak vs 8 before.
// ---------------------------------------------------------------------------
__global__ __launch_bounds__(128, 4) void energy_ctx_kernel(
    const float* __restrict__ values, const float* __restrict__ cum,
    const float* __restrict__ qbuf,
    const unsigned short* __restrict__ Bph, const unsigned short* __restrict__ Bpl,
    const unsigned short* __restrict__ effh, const unsigned short* __restrict__ effl,
    const float* __restrict__ vw, const unsigned char* __restrict__ mask,
    float* __restrict__ wU, float* __restrict__ bstats,
    float* __restrict__ ctxpart)
{
    __shared__ float sxw[2][80];   // per-wave cum window [t0w-15 .. t0w+64]
    __shared__ float sew[2][32];   // per-wave energies -> weights

    const int tid  = threadIdx.x;
    const int bx   = blockIdx.x;
    const int b    = bx >> 5;
    const int sub  = bx & 31;
    const int w    = tid >> 6;            // wave in block (0/1), independent
    const int lane = tid & 63;
    const int t0w  = sub * 64 + w * 32;   // this wave's 32 rows
    const int cid  = sub * 2 + w;         // chunk id 0..63 for combine

    const int lane15 = lane & 15;
    const int quad   = lane >> 4;

    // per-wave cum window (no barrier: same-wave LDS write->read, lgkmcnt only)
    {
        int g = t0w - 15 + lane;
        sxw[w][lane] = (g >= 0 && g < T_) ? cum[b * T_ + g] : 0.f;
        if (lane < 16) {
            int g2 = t0w + 49 + lane;
            sxw[w][64 + lane] = (g2 >= 0 && g2 < T_) ? cum[b * T_ + g2] : 0.f;
        }
    }

    f32x4 acc[2][8];
    #pragma unroll
    for (int i = 0; i < 2; ++i)
        #pragma unroll
        for (int j = 0; j < 8; ++j) acc[i][j] = (f32x4){0.f, 0.f, 0.f, 0.f};

    const float* abase = values + ((size_t)b * T_ + t0w + lane15) * ENC_ + quad * 8;
    const unsigned short* bbh = Bph + lane15 * 32 + quad * 8;
    const unsigned short* bbl = Bpl + lane15 * 32 + quad * 8;

    float4 pf[2][2];
    #pragma unroll
    for (int i = 0; i < 2; ++i) {
        pf[i][0] = *(const float4*)(abase + i * 16 * ENC_);
        pf[i][1] = *(const float4*)(abase + i * 16 * ENC_ + 4);
    }

    for (int kc = 0; kc < ENC_; kc += 32) {
        short8 ah[2], al[2];
        #pragma unroll
        for (int i = 0; i < 2; ++i) {
            float fb[8] = {pf[i][0].x, pf[i][0].y, pf[i][0].z, pf[i][0].w,
                           pf[i][1].x, pf[i][1].y, pf[i][1].z, pf[i][1].w};
            cvt_split8_exact(fb, ah[i], al[i]);
        }
        // B fragments (L2) issued BEFORE the HBM prefetch
        short8 bh[8], bl[8];
        const int chunk = (kc >> 5) * 4096;
        #pragma unroll
        for (int j = 0; j < 8; ++j) {
            bh[j] = *(const short8*)(bbh + chunk + j * 512);
            bl[j] = *(const short8*)(bbl + chunk + j * 512);
        }
        __builtin_amdgcn_sched_barrier(0);
        if (kc + 32 < ENC_) {
            #pragma unroll
            for (int i = 0; i < 2; ++i) {
                pf[i][0] = *(const float4*)(abase + i * 16 * ENC_ + kc + 32);
                pf[i][1] = *(const float4*)(abase + i * 16 * ENC_ + kc + 36);
            }
        }
        __builtin_amdgcn_sched_barrier(0);
        #pragma unroll
        for (int j = 0; j < 8; ++j)
            #pragma unroll
            for (int i = 0; i < 2; ++i) {
                acc[i][j] = __builtin_amdgcn_mfma_f32_16x16x32_bf16(ah[i], bh[j], acc[i][j], 0, 0, 0);
                acc[i][j] = __builtin_amdgcn_mfma_f32_16x16x32_bf16(ah[i], bl[j], acc[i][j], 0, 0, 0);
                acc[i][j] = __builtin_amdgcn_mfma_f32_16x16x32_bf16(al[i], bh[j], acc[i][j], 0, 0, 0);
            }
    }

    // ---- loc conv as MFMA: A' Toeplitz built from sxw in-register ----
    {
        short8 ah[2], al[2];
        #pragma unroll
        for (int i = 0; i < 2; ++i) {
            int base = i * 16 + lane15 + quad * 8;
            float xv[8];
            #pragma unroll
            for (int j2 = 0; j2 < 8; ++j2) xv[j2] = sxw[w][base + j2];
            cvt_split8_exact(xv, ah[i], al[i]);
        }
        #pragma unroll
        for (int j = 0; j < 8; ++j) {
            int n = j * 16 + lane15;
            short8 bh = *(const short8*)(effh + n * 32 + quad * 8);
            short8 bl = *(const short8*)(effl + n * 32 + quad * 8);
            #pragma unroll
            for (int i = 0; i < 2; ++i) {
                acc[i][j] = __builtin_amdgcn_mfma_f32_16x16x32_bf16(ah[i], bh, acc[i][j], 0, 0, 0);
                acc[i][j] = __builtin_amdgcn_mfma_f32_16x16x32_bf16(ah[i], bl, acc[i][j], 0, 0, 0);
                acc[i][j] = __builtin_amdgcn_mfma_f32_16x16x32_bf16(al[i], bh, acc[i][j], 0, 0, 0);
            }
        }
    }

    // ---- energies: E[t] = sum_n vw[n]*tanhf(acc + q[n]) -> sew[w][32] ----
    float qv[8], vv[8];
    #pragma unroll
    for (int j = 0; j < 8; ++j) {
        int n = j * 16 + lane15;
        qv[j] = qbuf[b * ATT_ + n];
        vv[j] = vw[n];
    }
    #pragma unroll
    for (int i = 0; i < 2; ++i)
        #pragma unroll
        for (int r = 0; r < 4; ++r) {
            float s = 0.f;
            #pragma unroll
            for (int j = 0; j < 8; ++j)
                s += vv[j] * tanhf(acc[i][j][r] + qv[j]);
            #pragma unroll
            for (int m = 8; m >= 1; m >>= 1) s += __shfl_xor(s, m, 64);
            if (lane15 == 0)
                sew[w][i * 16 + quad * 4 + r] = s;
        }

    // ---- local (32-row) max + sum, weights (in-wave, no barrier) ----
    float e = (lane < 32) ? sew[w][lane] : -INFINITY;
    if (lane < 32 && mask[b * T_ + t0w + lane]) e = -INFINITY;
    float mx = e;
    #pragma unroll
    for (int m = 32; m >= 1; m >>= 1) mx = fmaxf(mx, __shfl_xor(mx, m, 64));
    float w0 = 0.f;
    if (mx > -INFINITY && lane < 32) w0 = expf(e - mx);
    float sm = w0;
    #pragma unroll
    for (int m = 32; m >= 1; m >>= 1) sm += __shfl_xor(sm, m, 64);

    if (lane < 32) {
        sew[w][lane] = w0;
        wU[b * T_ + t0w + lane] = w0;
    }
    if (lane == 0)
        *(float2*)(bstats + (b * 64 + cid) * 2) = make_float2(mx, sm);

    // ---- partial context: each lane owns 8 cols; rows just streamed (L2) ----
    {
        int e8 = lane * 8;
        const float* vp = values + ((size_t)b * T_ + t0w) * ENC_ + e8;
        float4 c0 = make_float4(0.f, 0.f, 0.f, 0.f);
        float4 c1 = make_float4(0.f, 0.f, 0.f, 0.f);
        #pragma unroll 8
        for (int t = 0; t < 32; ++t) {
            float4 v0 = *(const float4*)(vp + (size_t)t * ENC_);
            float4 v1 = *(const float4*)(vp + (size_t)t * ENC_ + 4);
            float wv = sew[w][t];
            c0.x += wv * v0.x; c0.y += wv * v0.y;
            c0.z += wv * v0.z; c0.w += wv * v0.w;
            c1.x += wv * v1.x; c1.y += wv * v1.y;
            c1.z += wv * v1.z; c1.w += wv * v1.w;
        }
        float* cp = ctxpart + (size_t)(b * 64 + cid) * ENC_ + e8;
        *(float4*)(cp)     = c0;
        *(float4*)(cp + 4) = c1;
    }
}

// ---------------------------------------------------------------------------
// K3: combine 64 chunk-partials per b -> ctx + weights
// ---------------------------------------------------------------------------
__global__ __launch_bounds__(256) void combine_kernel(
    const float* __restrict__ bstats, const float* __restrict__ ctxpart,
    const float* __restrict__ wU, float* __restrict__ out)
{
    int b = blockIdx.x, tid = threadIdx.x;
    __shared__ float smx[64], ssm[64], ssc[64];
    if (tid < 64) {
        float2 st = *(const float2*)(bstats + (b * 64 + tid) * 2);
        smx[tid] = st.x; ssm[tid] = st.y;
    }
    __syncthreads();
    float M = -INFINITY;
    #pragma unroll
    for (int k = 0; k < 64; ++k) M = fmaxf(M, smx[k]);
    if (tid < 64)
        ssc[tid] = (smx[tid] > -INFINITY) ? expf(smx[tid] - M) : 0.f;
    __syncthreads();
    float S = 0.f;
    #pragma unroll
    for (int k = 0; k < 64; ++k) S += ssm[k] * ssc[k];
    float invS = 1.f / S;

    float* ctx  = out;
    float* wout = out + B_ * ENC_;

    float cx = 0.f, cy = 0.f;
    #pragma unroll 8
    for (int k = 0; k < 64; ++k) {
        float2 v = *(const float2*)(ctxpart + (size_t)(b * 64 + k) * ENC_ + tid * 2);
        cx += v.x * ssc[k]; cy += v.y * ssc[k];
    }
    *(float2*)(ctx + b * ENC_ + tid * 2) = make_float2(cx * invS, cy * invS);

    #pragma unroll
    for (int p = 0; p < 8; ++p) {
        int t = p * 256 + tid;
        wout[b * T_ + t] = wU[b * T_ + t] * ssc[t >> 5] * invS;
    }
}

// ---------------------------------------------------------------------------
extern "C" void kernel_launch(void* const* d_in, const int* in_sizes, int n_in,
                              void* d_out, int out_size, void* d_ws, size_t ws_size,
                              hipStream_t stream) {
    const float* query        = (const float*)d_in[0];
    const float* values       = (const float*)d_in[1];
    const float* cum          = (const float*)d_in[2];
    const unsigned char* mask = (const unsigned char*)d_in[3];
    const float* Q_w          = (const float*)d_in[4];
    const float* Q_b          = (const float*)d_in[5];
    const float* V_w          = (const float*)d_in[6];
    const float* conv_w       = (const float*)d_in[7];
    const float* loc_proj_w   = (const float*)d_in[8];
    const float* v_w          = (const float*)d_in[9];

    float* out = (float*)d_out;
    char*  ws  = (char*)d_ws;
    // ws layout (bytes):
    //  qbuf @0 (32 KB) | Bph @32768 (128 KB) | Bpl @163840 (128 KB)
    //  effh @294912 (8 KB) | effl @303104 (8 KB) | wU @311296 (512 KB)
    //  bstats @835584 (32 KB: 4096 x float2) | ctxpart @868352 (8 MB: 4096 x 512)
    float*          qbuf     = (float*)(ws);
    unsigned short* Bph      = (unsigned short*)(ws + 32768);
    unsigned short* Bpl      = (unsigned short*)(ws + 163840);
    unsigned short* effh     = (unsigned short*)(ws + 294912);
    unsigned short* effl     = (unsigned short*)(ws + 303104);
    float*          wU       = (float*)(ws + 311296);
    float*          bstats   = (float*)(ws + 835584);
    float*          ctxpart  = (float*)(ws + 868352);

    prep_kernel<<<289, 256, 0, stream>>>(query, Q_w, Q_b, conv_w, loc_proj_w, V_w,
                                         qbuf, Bph, Bpl, effh, effl);
    energy_ctx_kernel<<<2048, 128, 0, stream>>>(values, cum, qbuf, Bph, Bpl,
                                                effh, effl, v_w, mask,
                                                wU, bstats, ctxpart);
    combine_kernel<<<B_, 256, 0, stream>>>(bstats, ctxpart, wU, out);
}

// Round 10
// 458.775 us; speedup vs baseline: 1.6796x; 1.6796x over previous
//
#include <hip/hip_runtime.h>
#include <hip/hip_bf16.h>
#include <math.h>

// Problem constants
#define B_  64
#define T_  2048
#define DEC_ 1024
#define ENC_ 512
#define ATT_ 128
#define LOC_ 32
#define KW_  31

typedef __attribute__((ext_vector_type(8))) short short8;
typedef __attribute__((ext_vector_type(4))) float f32x4;

__device__ inline unsigned short bf16_rn(float x) {
    unsigned int u = __builtin_bit_cast(unsigned int, x);
    unsigned int r = u + 0x7fffu + ((u >> 16) & 1u);
    return (unsigned short)(r >> 16);
}
__device__ inline float bf16_to_f(unsigned short h) {
    unsigned int u = ((unsigned int)h) << 16;
    return __builtin_bit_cast(float, u);
}
__device__ inline void cvt_pair(float4 a, float4 b2, short8& hi, short8& lo) {
    float f[8] = {a.x, a.y, a.z, a.w, b2.x, b2.y, b2.z, b2.w};
    #pragma unroll
    for (int j = 0; j < 8; ++j) {
        unsigned short h = bf16_rn(f[j]);
        hi[j] = (short)h;
        lo[j] = (short)bf16_rn(f[j] - bf16_to_f(h));
    }
}

// ---------------------------------------------------------------------------
// K1: prep
//  blocks 0..255  : qbuf[b][a] = query[b].Q_w[a]+Q_b[a]
//  block  256     : eff[n][k] -> bf16 hi/lo at effh/effl[n*32+k]
//  blocks 257..288: V_w -> bf16 hi/lo packed frag layout
// ---------------------------------------------------------------------------
__global__ __launch_bounds__(256) void prep_kernel(
    const float* __restrict__ query, const float* __restrict__ Q_w,
    const float* __restrict__ Q_b, const float* __restrict__ conv_w,
    const float* __restrict__ loc_proj_w, const float* __restrict__ V_w,
    float* __restrict__ qbuf,
    unsigned short* __restrict__ Bph, unsigned short* __restrict__ Bpl,
    unsigned short* __restrict__ effh, unsigned short* __restrict__ effl)
{
    int bi = blockIdx.x, tid = threadIdx.x;
    if (bi < 256) {
        int b = bi >> 2, grp = bi & 3;
        __shared__ float sq[DEC_];
        *(float4*)(&sq[tid * 4]) = *(const float4*)(query + (size_t)b * DEC_ + tid * 4);
        __syncthreads();
        int w = tid >> 6, lane = tid & 63;
        int a0 = grp * 32 + w * 8;
        for (int p = 0; p < 4; ++p) {
            int a = a0 + 2 * p;
            const float* r0 = Q_w + (size_t)a * DEC_;
            const float* r1 = r0 + DEC_;
            float s0 = 0.f, s1 = 0.f;
            #pragma unroll
            for (int i = 0; i < 4; ++i) {
                float4 q0 = *(const float4*)(r0 + i * 256 + lane * 4);
                float4 q1 = *(const float4*)(r1 + i * 256 + lane * 4);
                float4 xq = *(const float4*)(sq + i * 256 + lane * 4);
                s0 += q0.x * xq.x + q0.y * xq.y + q0.z * xq.z + q0.w * xq.w;
                s1 += q1.x * xq.x + q1.y * xq.y + q1.z * xq.z + q1.w * xq.w;
            }
            #pragma unroll
            for (int m = 32; m >= 1; m >>= 1) {
                s0 += __shfl_xor(s0, m, 64);
                s1 += __shfl_xor(s1, m, 64);
            }
            if (lane == 0) {
                qbuf[b * ATT_ + a]     = s0 + Q_b[a];
                qbuf[b * ATT_ + a + 1] = s1 + Q_b[a + 1];
            }
        }
    } else if (bi == 256) {
        __shared__ float slp[ATT_ * LOC_];
        __shared__ float scw[LOC_ * KW_];
        for (int i = tid; i < ATT_ * LOC_; i += 256) slp[i] = loc_proj_w[i];
        for (int i = tid; i < LOC_ * KW_; i += 256) scw[i] = conv_w[i];
        __syncthreads();
        if (tid < ATT_) {
            int n = tid;
            for (int k = 0; k < 32; ++k) {
                float s = 0.f;
                if (k < KW_)
                    #pragma unroll
                    for (int c = 0; c < LOC_; ++c)
                        s += slp[n * LOC_ + c] * scw[c * KW_ + k];
                unsigned short h = bf16_rn(s);
                effh[n * 32 + k] = h;
                effl[n * 32 + k] = bf16_rn(s - bf16_to_f(h));
            }
        }
    } else {
        int g0 = (bi - 257) * 512;
        #pragma unroll
        for (int p = 0; p < 2; ++p) {
            int gi = g0 + p * 256 + tid;
            int n  = gi >> 7;
            int kq = (gi & 127) * 4;
            float4 v = ((const float4*)V_w)[gi];
            ushort4 h4, l4;
            h4.x = bf16_rn(v.x); l4.x = bf16_rn(v.x - bf16_to_f(h4.x));
            h4.y = bf16_rn(v.y); l4.y = bf16_rn(v.y - bf16_to_f(h4.y));
            h4.z = bf16_rn(v.z); l4.z = bf16_rn(v.z - bf16_to_f(h4.z));
            h4.w = bf16_rn(v.w); l4.w = bf16_rn(v.w - bf16_to_f(h4.w));
            int dst = (kq >> 5) * 4096 + n * 32 + (kq & 31);
            *(ushort4*)(Bph + dst) = h4;
            *(ushort4*)(Bpl + dst) = l4;
        }
    }
}

// ---------------------------------------------------------------------------
// K2 (FUSED): energies via direct-fragment split-bf16 MFMA, then flash-style
// LOCAL softmax (per 128-t chunk) + PARTIAL context, re-reading this block's
// own 256 KB values chunk while it is still L2/L3-resident.
// ---------------------------------------------------------------------------
__global__ __launch_bounds__(256, 2) void energy_ctx_kernel(
    const float* __restrict__ values, const float* __restrict__ cum,
    const float* __restrict__ qbuf,
    const unsigned short* __restrict__ Bph, const unsigned short* __restrict__ Bpl,
    const unsigned short* __restrict__ effh, const unsigned short* __restrict__ effl,
    const float* __restrict__ vw, const unsigned char* __restrict__ mask,
    float* __restrict__ wU, float* __restrict__ bstats,
    float* __restrict__ ctxpart)
{
    __shared__ float sx[160];
    __shared__ float se[128];
    __shared__ float red[512];

    const int tid = threadIdx.x;
    const int bx  = blockIdx.x;
    const int b   = bx >> 4;
    const int t0  = (bx & 15) * 128;

    if (tid < 160) {
        int g = t0 - 15 + tid;
        sx[tid] = (g >= 0 && g < T_) ? cum[b * T_ + g] : 0.f;
    }
    __syncthreads();

    const int w      = tid >> 6;
    const int lane   = tid & 63;
    const int lane15 = lane & 15;
    const int quad   = lane >> 4;

    f32x4 acc[2][8];
    #pragma unroll
    for (int i = 0; i < 2; ++i)
        #pragma unroll
        for (int j = 0; j < 8; ++j) acc[i][j] = (f32x4){0.f, 0.f, 0.f, 0.f};

    const float* abase = values + ((size_t)b * T_ + t0 + w * 32 + lane15) * ENC_ + quad * 8;
    const unsigned short* bbh = Bph + lane15 * 32 + quad * 8;
    const unsigned short* bbl = Bpl + lane15 * 32 + quad * 8;

    float4 pf[2][2];
    #pragma unroll
    for (int i = 0; i < 2; ++i) {
        pf[i][0] = *(const float4*)(abase + i * 16 * ENC_);
        pf[i][1] = *(const float4*)(abase + i * 16 * ENC_ + 4);
    }

    for (int kc = 0; kc < ENC_; kc += 32) {
        short8 ah[2], al[2];
        #pragma unroll
        for (int i = 0; i < 2; ++i) cvt_pair(pf[i][0], pf[i][1], ah[i], al[i]);

        // B fragments (L2) issued BEFORE the HBM prefetch
        short8 bh[8], bl[8];
        const int chunk = (kc >> 5) * 4096;
        #pragma unroll
        for (int j = 0; j < 8; ++j) {
            bh[j] = *(const short8*)(bbh + chunk + j * 512);
            bl[j] = *(const short8*)(bbl + chunk + j * 512);
        }
        __builtin_amdgcn_sched_barrier(0);
        if (kc + 32 < ENC_) {
            #pragma unroll
            for (int i = 0; i < 2; ++i) {
                pf[i][0] = *(const float4*)(abase + i * 16 * ENC_ + kc + 32);
                pf[i][1] = *(const float4*)(abase + i * 16 * ENC_ + kc + 36);
            }
        }
        __builtin_amdgcn_sched_barrier(0);
        #pragma unroll
        for (int j = 0; j < 8; ++j)
            #pragma unroll
            for (int i = 0; i < 2; ++i) {
                acc[i][j] = __builtin_amdgcn_mfma_f32_16x16x32_bf16(ah[i], bh[j], acc[i][j], 0, 0, 0);
                acc[i][j] = __builtin_amdgcn_mfma_f32_16x16x32_bf16(ah[i], bl[j], acc[i][j], 0, 0, 0);
                acc[i][j] = __builtin_amdgcn_mfma_f32_16x16x32_bf16(al[i], bh[j], acc[i][j], 0, 0, 0);
            }
    }

    // ---- loc conv as MFMA: A' Toeplitz built from sx in-register ----
    {
        short8 ah[2], al[2];
        #pragma unroll
        for (int i = 0; i < 2; ++i) {
            int base = w * 32 + i * 16 + lane15 + quad * 8;
            #pragma unroll
            for (int j2 = 0; j2 < 8; ++j2) {
                float xv = sx[base + j2];           // k=31 column killed by eff==0
                unsigned short h = bf16_rn(xv);
                ah[i][j2] = (short)h;
                al[i][j2] = (short)bf16_rn(xv - bf16_to_f(h));
            }
        }
        #pragma unroll
        for (int j = 0; j < 8; ++j) {
            int n = j * 16 + lane15;
            short8 bh = *(const short8*)(effh + n * 32 + quad * 8);
            short8 bl = *(const short8*)(effl + n * 32 + quad * 8);
            #pragma unroll
            for (int i = 0; i < 2; ++i) {
                acc[i][j] = __builtin_amdgcn_mfma_f32_16x16x32_bf16(ah[i], bh, acc[i][j], 0, 0, 0);
                acc[i][j] = __builtin_amdgcn_mfma_f32_16x16x32_bf16(ah[i], bl, acc[i][j], 0, 0, 0);
                acc[i][j] = __builtin_amdgcn_mfma_f32_16x16x32_bf16(al[i], bh, acc[i][j], 0, 0, 0);
            }
        }
    }

    // ---- energies: E[t] = sum_n vw[n]*tanhf(acc + q[n]) -> LDS se[128] ----
    float qv[8], vv[8];
    #pragma unroll
    for (int j = 0; j < 8; ++j) {
        int n = j * 16 + lane15;
        qv[j] = qbuf[b * ATT_ + n];
        vv[j] = vw[n];
    }
    #pragma unroll
    for (int i = 0; i < 2; ++i)
        #pragma unroll
        for (int r = 0; r < 4; ++r) {
            float s = 0.f;
            #pragma unroll
            for (int j = 0; j < 8; ++j)
                s += vv[j] * tanhf(acc[i][j][r] + qv[j]);
            #pragma unroll
            for (int m = 8; m >= 1; m >>= 1) s += __shfl_xor(s, m, 64);
            if (lane15 == 0)
                se[w * 32 + i * 16 + quad * 4 + r] = s;
        }
    __syncthreads();

    // ---- mask, then local (chunk) max + sum: every wave reduces all 128 ----
    if (tid < 128 && mask[b * T_ + t0 + tid]) se[tid] = -INFINITY;
    __syncthreads();

    float e0 = se[lane * 2], e1 = se[lane * 2 + 1];
    float mx = fmaxf(e0, e1);
    #pragma unroll
    for (int m = 32; m >= 1; m >>= 1) mx = fmaxf(mx, __shfl_xor(mx, m, 64));
    float w0 = 0.f, w1 = 0.f;
    if (mx > -INFINITY) {                // all-masked chunk -> weights 0
        w0 = expf(e0 - mx);              // expf(-inf)=0 handles masked rows
        w1 = expf(e1 - mx);
    }
    float sm = w0 + w1;
    #pragma unroll
    for (int m = 32; m >= 1; m >>= 1) sm += __shfl_xor(sm, m, 64);
    __syncthreads();                     // all reads of se done before overwrite

    if (w == 0) {                        // wave 0 publishes (values identical per wave)
        se[lane * 2]     = w0;
        se[lane * 2 + 1] = w1;
        *(float2*)(wU + b * T_ + t0 + lane * 2) = make_float2(w0, w1);
        if (lane == 0)
            *(float2*)(bstats + bx * 2) = make_float2(mx, sm);
    }
    __syncthreads();

    // ---- partial context: ctxpart[bx][e] = sum_{t in chunk} w_t * values ----
    // This block's 256 KB chunk was just streamed -> L2/L3 resident.
    {
        int tt = tid >> 7;               // 0..1 : t-half
        int e4 = (tid & 127) * 4;        // 128 threads * float4 = 512 cols
        const float* vp = values + ((size_t)b * T_ + t0 + tt * 64) * ENC_ + e4;
        float4 cacc = make_float4(0.f, 0.f, 0.f, 0.f);
        #pragma unroll 8
        for (int t = 0; t < 64; ++t) {
            float4 v = *(const float4*)(vp + (size_t)t * ENC_);
            float wv = se[tt * 64 + t];
            cacc.x += wv * v.x; cacc.y += wv * v.y;
            cacc.z += wv * v.z; cacc.w += wv * v.w;
        }
        if (tt == 1) *(float4*)&red[e4] = cacc;
        __syncthreads();
        if (tt == 0) {
            float4 o = *(const float4*)&red[e4];
            float4 tot = make_float4(cacc.x + o.x, cacc.y + o.y,
                                     cacc.z + o.z, cacc.w + o.w);
            *(float4*)(ctxpart + (size_t)bx * ENC_ + e4) = tot;
        }
    }
}

// ---------------------------------------------------------------------------
// K3: combine 16 chunk-partials per b: global max/sum rescale -> ctx + weights
// ---------------------------------------------------------------------------
__global__ __launch_bounds__(256) void combine_kernel(
    const float* __restrict__ bstats, const float* __restrict__ ctxpart,
    const float* __restrict__ wU, float* __restrict__ out)
{
    int b = blockIdx.x, tid = threadIdx.x;
    __shared__ float smx[16], ssm[16], ssc[16];
    if (tid < 16) {
        float2 st = *(const float2*)(bstats + (b * 16 + tid) * 2);
        smx[tid] = st.x; ssm[tid] = st.y;
    }
    __syncthreads();
    float M = -INFINITY;
    #pragma unroll
    for (int k = 0; k < 16; ++k) M = fmaxf(M, smx[k]);
    if (tid < 16)
        ssc[tid] = (smx[tid] > -INFINITY) ? expf(smx[tid] - M) : 0.f;
    __syncthreads();
    float S = 0.f;
    #pragma unroll
    for (int k = 0; k < 16; ++k) S += ssm[k] * ssc[k];
    float invS = 1.f / S;

    float* ctx  = out;                   // B*ENC
    float* wout = out + B_ * ENC_;       // B*T

    // context: 512 cols, float2 per thread
    float cx = 0.f, cy = 0.f;
    #pragma unroll
    for (int k = 0; k < 16; ++k) {
        float2 v = *(const float2*)(ctxpart + (size_t)(b * 16 + k) * ENC_ + tid * 2);
        cx += v.x * ssc[k]; cy += v.y * ssc[k];
    }
    *(float2*)(ctx + b * ENC_ + tid * 2) = make_float2(cx * invS, cy * invS);

    // weights: wout = wU * exp(mx_k - M) / S
    #pragma unroll
    for (int p = 0; p < 8; ++p) {
        int t = p * 256 + tid;
        wout[b * T_ + t] = wU[b * T_ + t] * ssc[t >> 7] * invS;
    }
}

// ---------------------------------------------------------------------------
extern "C" void kernel_launch(void* const* d_in, const int* in_sizes, int n_in,
                              void* d_out, int out_size, void* d_ws, size_t ws_size,
                              hipStream_t stream) {
    const float* query        = (const float*)d_in[0];
    const float* values       = (const float*)d_in[1];
    const float* cum          = (const float*)d_in[2];
    const unsigned char* mask = (const unsigned char*)d_in[3];
    const float* Q_w          = (const float*)d_in[4];
    const float* Q_b          = (const float*)d_in[5];
    const float* V_w          = (const float*)d_in[6];
    const float* conv_w       = (const float*)d_in[7];
    const float* loc_proj_w   = (const float*)d_in[8];
    const float* v_w          = (const float*)d_in[9];

    float* out = (float*)d_out;
    char*  ws  = (char*)d_ws;
    // ws layout (bytes):
    //  qbuf @0 (32 KB) | Bph @32768 (128 KB) | Bpl @163840 (128 KB)
    //  effh @294912 (8 KB) | effl @303104 (8 KB) | wU @311296 (512 KB)
    //  bstats @835584 (8 KB) | ctxpart @843776 (2 MB)
    float*          qbuf     = (float*)(ws);
    unsigned short* Bph      = (unsigned short*)(ws + 32768);
    unsigned short* Bpl      = (unsigned short*)(ws + 163840);
    unsigned short* effh     = (unsigned short*)(ws + 294912);
    unsigned short* effl     = (unsigned short*)(ws + 303104);
    float*          wU       = (float*)(ws + 311296);
    float*          bstats   = (float*)(ws + 835584);
    float*          ctxpart  = (float*)(ws + 843776);

    prep_kernel<<<289, 256, 0, stream>>>(query, Q_w, Q_b, conv_w, loc_proj_w, V_w,
                                         qbuf, Bph, Bpl, effh, effl);
    energy_ctx_kernel<<<1024, 256, 0, stream>>>(values, cum, qbuf, Bph, Bpl,
                                                effh, effl, v_w, mask,
                                                wU, bstats, ctxpart);
    combine_kernel<<<B_, 256, 0, stream>>>(bstats, ctxpart, wU, out);
}